// Round 4
// baseline (288.541 us; speedup 1.0000x reference)
//
#include <hip/hip_runtime.h>
#include <hip/hip_cooperative_groups.h>
#include <cstdint>
#include <cstddef>

namespace cg = cooperative_groups;

#define NB 4
#define CH 256
#define SS 4096
#define EE 128
#define QSCALE 0.08838834764831845f /* 1/sqrt(128) */

typedef __attribute__((ext_vector_type(8))) short bfrag;          // 8 bf16 = 4 VGPR
typedef __attribute__((ext_vector_type(8))) unsigned short u16x8; // 16B store
typedef __attribute__((ext_vector_type(4))) float f32x4;          // MFMA acc

__device__ __forceinline__ unsigned short f2bf(float f) {
  union { float f; unsigned int u; } v; v.f = f;
  unsigned int u = v.u;
  unsigned int r = u + 0x7FFFu + ((u >> 16) & 1u);  // RNE
  return (unsigned short)(r >> 16);
}

// ---------------------------------------------------------------------------
// Single cooperative kernel: 256 blocks x 512 threads, 1 block/CU.
// Phase A (pass1): stage x fp32->bf16 (write xb), compute theta/phi
//   projections with weights converted inline from fp32. Q-tile -> LDS only
//   (consumed by this block); K-tile -> global Kt (consumed by all blocks).
// grid.sync()
// Phase B (pass2+3): round-3 flash-attention loop (unchanged) + fused
//   projection epilogue with proj_w converted inline from fp32.
// LDS time-share: phase A xT[64][264]+Qlds[64][136] alias phase B S/P bufs.
// XCD swizzle: n=(id&7)>>1 pins each image to 2 XCDs; phase A writes and
//   phase B reads of K/V then stay mostly XCD-local.
// ---------------------------------------------------------------------------
__global__ __launch_bounds__(512, 2) void fused_all(
    const float* __restrict__ x,
    const float* __restrict__ thw,
    const float* __restrict__ phw,
    const float* __restrict__ pw,
    unsigned short* __restrict__ xb,
    unsigned short* __restrict__ Kt,
    float* __restrict__ out)
{
  //   [0      .. 33792)  A: xT u16[64][264]   | B: S_lds f32[64][132] / Y_lds u16[64][264]
  //   [33792  .. 51200)  A: Qlds u16[64][136] | B: P_lds u16[64][136]
  //   [51200  .. 51456)  row_m  float[64]
  //   [51456  .. 51712)  row_l  float[64]
  //   [51712  .. 51968)  row_alpha float[64]
  __shared__ __align__(16) unsigned char SMEM[51968];

  const int t    = threadIdx.x;
  const int id   = blockIdx.x;
  const int xcd  = id & 7;                    // presumed HW XCD of this block
  const int n    = xcd >> 1;                  // pin each image to 2 XCDs
  const int s0   = ((id >> 3) * 2 + (xcd & 1)) * 64;  // bijective: 64 tiles/n
  const int w    = t >> 6;      // 0..7
  const int lane = t & 63;
  const int q    = lane >> 4;
  const int mr   = lane & 15;

  // ======================= Phase A: projections =======================
  {
    unsigned short (*xT)[CH + 8] =
        reinterpret_cast<unsigned short(*)[CH + 8]>(SMEM);
    unsigned short (*Qlds)[136] =
        reinterpret_cast<unsigned short(*)[136]>(SMEM + 33792);

    // stage: fp32 reads along s (coalesced), cvt, xb write, transposed LDS
    {
      const int soff = (t & 15) * 4;
      const int c0   = t >> 4;           // 0..31
      #pragma unroll
      for (int ci = 0; ci < 8; ++ci) {
        const int c = c0 + ci * 32;
        const size_t rowoff = ((size_t)n * CH + c) * SS + s0;
        float4 v = reinterpret_cast<const float4*>(x + rowoff)[soff >> 2];
        ushort4 o;
        o.x = f2bf(v.x); o.y = f2bf(v.y); o.z = f2bf(v.z); o.w = f2bf(v.w);
        reinterpret_cast<ushort4*>(xb + rowoff)[soff >> 2] = o;
        xT[soff + 0][c] = o.x;
        xT[soff + 1][c] = o.y;
        xT[soff + 2][c] = o.z;
        xT[soff + 3][c] = o.w;
      }
    }
    __syncthreads();

    const int wrow = (w & 3) * 16;  // s-rows within tile
    const int half = w >> 2;        // 0: theta->Qlds, 1: phi->Kt

    bfrag a[8];
    {
      const bfrag* rp = reinterpret_cast<const bfrag*>(&xT[wrow + mr][0]);
      #pragma unroll
      for (int k = 0; k < 8; ++k) a[k] = rp[k * 4 + q];
    }

    const float* wsel = half ? phw : thw;
    #pragma unroll
    for (int nt = 0; nt < 8; ++nt) {
      f32x4 acc = {0.f, 0.f, 0.f, 0.f};
      const float4* wr4 =
          reinterpret_cast<const float4*>(wsel + (nt * 16 + mr) * CH);
      #pragma unroll
      for (int k = 0; k < 8; ++k) {
        float4 w0 = wr4[(k * 4 + q) * 2];
        float4 w1 = wr4[(k * 4 + q) * 2 + 1];
        bfrag b;
        b[0] = (short)f2bf(w0.x); b[1] = (short)f2bf(w0.y);
        b[2] = (short)f2bf(w0.z); b[3] = (short)f2bf(w0.w);
        b[4] = (short)f2bf(w1.x); b[5] = (short)f2bf(w1.y);
        b[6] = (short)f2bf(w1.z); b[7] = (short)f2bf(w1.w);
        acc = __builtin_amdgcn_mfma_f32_16x16x32_bf16(a[k], b, acc, 0, 0, 0);
      }
      if (half) {
        #pragma unroll
        for (int i = 0; i < 4; ++i) {
          const int srow = s0 + wrow + q * 4 + i;
          Kt[((size_t)n * SS + srow) * EE + nt * 16 + mr] = f2bf(acc[i]);
        }
      } else {
        #pragma unroll
        for (int i = 0; i < 4; ++i)
          Qlds[wrow + q * 4 + i][nt * 16 + mr] = f2bf(acc[i] * QSCALE);
      }
    }
    __syncthreads();
  }

  // Q fragments out of LDS into registers BEFORE SMEM is reused by phase B
  bfrag qa[4][4];
  {
    unsigned short (*Qlds)[136] =
        reinterpret_cast<unsigned short(*)[136]>(SMEM + 33792);
    #pragma unroll
    for (int ms = 0; ms < 4; ++ms) {
      const bfrag* rp = reinterpret_cast<const bfrag*>(&Qlds[ms * 16 + mr][0]);
      #pragma unroll
      for (int k = 0; k < 4; ++k) qa[ms][k] = rp[k * 4 + q];
    }
  }

  float* row_m     = reinterpret_cast<float*>(SMEM + 51200);
  float* row_l     = reinterpret_cast<float*>(SMEM + 51456);
  float* row_alpha = reinterpret_cast<float*>(SMEM + 51712);
  if (t < 64) { row_m[t] = -INFINITY; row_l[t] = 0.f; }

  __threadfence();           // device-scope release of Kt/xb
  cg::this_grid().sync();    // all Kt/xb visible to all blocks

  // ======================= Phase B: attention + projection =======================
  float          (*S_lds)[132] = reinterpret_cast<float(*)[132]>(SMEM);
  unsigned short (*P_lds)[136] =
      reinterpret_cast<unsigned short(*)[136]>(SMEM + 33792);

  f32x4 o_acc[4][2];
  #pragma unroll
  for (int ms = 0; ms < 4; ++ms)
    #pragma unroll
    for (int nt = 0; nt < 2; ++nt) o_acc[ms][nt] = (f32x4){0.f, 0.f, 0.f, 0.f};

  // K fragments for iter 0 (wave w -> key col block w)
  bfrag kb[4];
  {
    const bfrag* rp = reinterpret_cast<const bfrag*>(
        Kt + ((size_t)n * SS + w * 16 + mr) * EE);
    #pragma unroll
    for (int k = 0; k < 4; ++k) kb[k] = rp[k * 4 + q];
  }

  for (int t0 = 0; t0 < SS; t0 += 128) {
    // ---- prefetch V fragments for THIS iter (consumed after softmax) ----
    bfrag vb[4][2];
    #pragma unroll
    for (int nt = 0; nt < 2; ++nt) {
      const int c = w * 32 + nt * 16 + mr;
      const bfrag* vp = reinterpret_cast<const bfrag*>(
          xb + ((size_t)n * CH + c) * SS + t0);
      #pragma unroll
      for (int kk = 0; kk < 4; ++kk) vb[kk][nt] = vp[kk * 4 + q];
    }

    // ---- QK^T: wave w -> 16 key cols ----
    #pragma unroll
    for (int ms = 0; ms < 4; ++ms) {
      f32x4 acc = {0.f, 0.f, 0.f, 0.f};
      #pragma unroll
      for (int k = 0; k < 4; ++k)
        acc = __builtin_amdgcn_mfma_f32_16x16x32_bf16(qa[ms][k], kb[k], acc, 0, 0, 0);
      #pragma unroll
      for (int i = 0; i < 4; ++i)
        S_lds[ms * 16 + q * 4 + i][w * 16 + mr] = acc[i];
    }
    __syncthreads();

    // ---- prefetch K fragments for NEXT iter ----
    {
      const int t1 = t0 + 128;
      if (t1 < SS) {
        const bfrag* rp = reinterpret_cast<const bfrag*>(
            Kt + ((size_t)n * SS + t1 + w * 16 + mr) * EE);
        #pragma unroll
        for (int k = 0; k < 4; ++k) kb[k] = rp[k * 4 + q];
      }
    }

    // ---- online softmax: 8 lanes/row, float4 reads, ushort8 P writes ----
    {
      const int r  = t >> 3;
      const int cg_ = t & 7;
      const float4* srow = reinterpret_cast<const float4*>(&S_lds[r][cg_ * 16]);
      float4 v0 = srow[0], v1 = srow[1], v2 = srow[2], v3 = srow[3];
      float vmax = fmaxf(fmaxf(fmaxf(v0.x, v0.y), fmaxf(v0.z, v0.w)),
                         fmaxf(fmaxf(v1.x, v1.y), fmaxf(v1.z, v1.w)));
      vmax = fmaxf(vmax, fmaxf(fmaxf(fmaxf(v2.x, v2.y), fmaxf(v2.z, v2.w)),
                               fmaxf(fmaxf(v3.x, v3.y), fmaxf(v3.z, v3.w))));
      vmax = fmaxf(vmax, __shfl_xor(vmax, 1, 8));
      vmax = fmaxf(vmax, __shfl_xor(vmax, 2, 8));
      vmax = fmaxf(vmax, __shfl_xor(vmax, 4, 8));
      const float m_old = row_m[r];
      const float m_new = fmaxf(m_old, vmax);

      float p[16];
      p[0]=__expf(v0.x-m_new); p[1]=__expf(v0.y-m_new); p[2]=__expf(v0.z-m_new); p[3]=__expf(v0.w-m_new);
      p[4]=__expf(v1.x-m_new); p[5]=__expf(v1.y-m_new); p[6]=__expf(v1.z-m_new); p[7]=__expf(v1.w-m_new);
      p[8]=__expf(v2.x-m_new); p[9]=__expf(v2.y-m_new); p[10]=__expf(v2.z-m_new); p[11]=__expf(v2.w-m_new);
      p[12]=__expf(v3.x-m_new); p[13]=__expf(v3.y-m_new); p[14]=__expf(v3.z-m_new); p[15]=__expf(v3.w-m_new);
      float sum = 0.f;
      u16x8 pk0, pk1;
      #pragma unroll
      for (int j = 0; j < 8; ++j) { sum += p[j];     pk0[j] = f2bf(p[j]); }
      #pragma unroll
      for (int j = 0; j < 8; ++j) { sum += p[8 + j]; pk1[j] = f2bf(p[8 + j]); }
      *reinterpret_cast<u16x8*>(&P_lds[r][cg_ * 16])     = pk0;
      *reinterpret_cast<u16x8*>(&P_lds[r][cg_ * 16 + 8]) = pk1;
      sum += __shfl_xor(sum, 1, 8);
      sum += __shfl_xor(sum, 2, 8);
      sum += __shfl_xor(sum, 4, 8);
      if (cg_ == 0) {
        const float al = __expf(m_old - m_new);   // exp(-inf)=0 on iter 0
        row_alpha[r] = al;
        row_m[r]     = m_new;
        row_l[r]     = row_l[r] * al + sum;
      }
    }
    __syncthreads();

    // ---- rescale O, then O += P @ V ----
    #pragma unroll
    for (int ms = 0; ms < 4; ++ms) {
      float al[4];
      #pragma unroll
      for (int i = 0; i < 4; ++i) al[i] = row_alpha[ms * 16 + q * 4 + i];
      #pragma unroll
      for (int nt = 0; nt < 2; ++nt)
        #pragma unroll
        for (int i = 0; i < 4; ++i) o_acc[ms][nt][i] *= al[i];
    }

    #pragma unroll
    for (int kk = 0; kk < 4; ++kk) {
      bfrag pa[4];
      #pragma unroll
      for (int ms = 0; ms < 4; ++ms)
        pa[ms] = reinterpret_cast<const bfrag*>(&P_lds[ms * 16 + mr][0])[kk * 4 + q];
      #pragma unroll
      for (int nt = 0; nt < 2; ++nt)
        #pragma unroll
        for (int ms = 0; ms < 4; ++ms)
          o_acc[ms][nt] = __builtin_amdgcn_mfma_f32_16x16x32_bf16(
              pa[ms], vb[kk][nt], o_acc[ms][nt], 0, 0, 0);
    }
  }

  // ---- fused epilogue: Y -> LDS, then out = x + pw @ Y^T ----
  __syncthreads();   // everyone done with S_lds/P_lds of the last iteration
  unsigned short (*Y_lds)[CH + 8] =
      reinterpret_cast<unsigned short(*)[CH + 8]>(SMEM);  // 64*264*2 = 33792 B

  #pragma unroll
  for (int ms = 0; ms < 4; ++ms) {
    float inv[4];
    #pragma unroll
    for (int i = 0; i < 4; ++i) inv[i] = 1.0f / row_l[ms * 16 + q * 4 + i];
    #pragma unroll
    for (int nt = 0; nt < 2; ++nt) {
      const int c = w * 32 + nt * 16 + mr;
      #pragma unroll
      for (int i = 0; i < 4; ++i)
        Y_lds[ms * 16 + q * 4 + i][c] = f2bf(o_acc[ms][nt][i] * inv[i]);
    }
  }
  __syncthreads();

  // projection: wave w computes output rows o = w*32 .. w*32+31
  #pragma unroll
  for (int ot = 0; ot < 2; ++ot) {
    const int o0 = w * 32 + ot * 16;
    bfrag a[8];
    {
      const float4* ar4 =
          reinterpret_cast<const float4*>(pw + (o0 + mr) * CH);
      #pragma unroll
      for (int k = 0; k < 8; ++k) {
        float4 w0 = ar4[(k * 4 + q) * 2];
        float4 w1 = ar4[(k * 4 + q) * 2 + 1];
        bfrag b;
        b[0] = (short)f2bf(w0.x); b[1] = (short)f2bf(w0.y);
        b[2] = (short)f2bf(w0.z); b[3] = (short)f2bf(w0.w);
        b[4] = (short)f2bf(w1.x); b[5] = (short)f2bf(w1.y);
        b[6] = (short)f2bf(w1.z); b[7] = (short)f2bf(w1.w);
        a[k] = b;
      }
    }
    #pragma unroll
    for (int st = 0; st < 4; ++st) {
      f32x4 acc = {0.f, 0.f, 0.f, 0.f};
      const bfrag* bp = reinterpret_cast<const bfrag*>(&Y_lds[st * 16 + mr][0]);
      #pragma unroll
      for (int k = 0; k < 8; ++k)
        acc = __builtin_amdgcn_mfma_f32_16x16x32_bf16(a[k], bp[k * 4 + q], acc, 0, 0, 0);
      #pragma unroll
      for (int i = 0; i < 4; ++i) {
        const int o = o0 + q * 4 + i;
        const int s = s0 + st * 16 + mr;
        const size_t idx = ((size_t)n * CH + o) * SS + s;
        out[idx] = x[idx] + acc[i];
      }
    }
  }
}

// ---------------------------------------------------------------------------
extern "C" void kernel_launch(void* const* d_in, const int* in_sizes, int n_in,
                              void* d_out, int out_size, void* d_ws, size_t ws_size,
                              hipStream_t stream) {
  const float* x   = (const float*)d_in[0];
  const float* thw = (const float*)d_in[1];
  const float* phw = (const float*)d_in[2];
  const float* pw  = (const float*)d_in[3];
  float* out = (float*)d_out;

  unsigned short* xb = (unsigned short*)d_ws;            // 8 MB bf16 x
  unsigned short* Kt = xb + (size_t)NB * CH * SS;        // 4 MB bf16 K

  void* args[] = {(void*)&x, (void*)&thw, (void*)&phw, (void*)&pw,
                  (void*)&xb, (void*)&Kt, (void*)&out};
  hipLaunchCooperativeKernel(reinterpret_cast<void*>(&fused_all),
                             dim3(NB * SS / 64), dim3(512), args, 0, stream);
}

// Round 5
// 195.834 us; speedup vs baseline: 1.4734x; 1.4734x over previous
//
#include <hip/hip_runtime.h>
#include <cstdint>
#include <cstddef>

#define NB 4
#define CH 256
#define SS 4096
#define EE 128
#define QSCALE 0.08838834764831845f /* 1/sqrt(128) */

typedef __attribute__((ext_vector_type(8))) short bfrag;          // 8 bf16 = 4 VGPR
typedef __attribute__((ext_vector_type(8))) unsigned short u16x8; // 16B store
typedef __attribute__((ext_vector_type(4))) float f32x4;          // MFMA acc

__device__ __forceinline__ unsigned short f2bf(float f) {
  union { float f; unsigned int u; } v; v.f = f;
  unsigned int u = v.u;
  unsigned int r = u + 0x7FFFu + ((u >> 16) & 1u);  // RNE
  return (unsigned short)(r >> 16);
}

// LDS-only barrier: waits DS ops, leaves global loads in flight (no vmcnt
// drain). "memory" clobber pins LDS stores before / loads after; compiler
// still inserts per-use vmcnt waits for register consumers of global loads.
__device__ __forceinline__ void lds_barrier() {
  asm volatile("s_waitcnt lgkmcnt(0)" ::: "memory");
  __builtin_amdgcn_s_barrier();
}

// ---------------------------------------------------------------------------
// Pass 0: weights-only fp32 -> bf16 (x conversion is fused into pass1)
// ---------------------------------------------------------------------------
__global__ __launch_bounds__(256) void cvt_w(
    const float* __restrict__ thw, const float* __restrict__ phw,
    const float* __restrict__ pw,
    unsigned short* __restrict__ thwb, unsigned short* __restrict__ phwb,
    unsigned short* __restrict__ pwb)
{
  const int nw4 = EE * CH / 4;   // 8192
  const int np4 = CH * CH / 4;   // 16384
  int i = blockIdx.x * 256 + threadIdx.x;
  const float* src; unsigned short* dst; int off;
  if      (i < nw4)           { src = thw; dst = thwb; off = i; }
  else if (i < 2 * nw4)       { src = phw; dst = phwb; off = i - nw4; }
  else if (i < 2 * nw4 + np4) { src = pw;  dst = pwb;  off = i - 2 * nw4; }
  else return;
  float4 v = reinterpret_cast<const float4*>(src)[off];
  ushort4 o;
  o.x = f2bf(v.x); o.y = f2bf(v.y); o.z = f2bf(v.z); o.w = f2bf(v.w);
  reinterpret_cast<ushort4*>(dst)[off] = o;
}

// ---------------------------------------------------------------------------
// Pass 1 (fused): per (n, s-tile) block of 512 threads:
//   - load x tile [256 c][64 s] as fp32, convert to bf16 in-register
//   - write xb (bf16 x, byproduct for pass2's V) with coalesced 8B stores
//   - stage transposed xT[s][c] in LDS (staged ONCE, shared by both halves)
//   - waves 0-3: Qt = QSCALE * theta_w @ x ; waves 4-7: Kt = phi_w @ x
// ---------------------------------------------------------------------------
__global__ __launch_bounds__(512) void pass1_qk(
    const float* __restrict__ x,
    const unsigned short* __restrict__ thw,
    const unsigned short* __restrict__ phw,
    unsigned short* __restrict__ xb,
    unsigned short* __restrict__ Qt,
    unsigned short* __restrict__ Kt)
{
  __shared__ unsigned short xT[64][CH + 8];
  const int t  = threadIdx.x;
  const int n  = blockIdx.y;
  const int s0 = blockIdx.x * 64;

  {
    const int soff = (t & 15) * 4;
    const int c0   = t >> 4;           // 0..31
    #pragma unroll
    for (int ci = 0; ci < 8; ++ci) {
      const int c = c0 + ci * 32;
      const size_t rowoff = ((size_t)n * CH + c) * SS + s0;
      float4 v = reinterpret_cast<const float4*>(x + rowoff)[soff >> 2];
      ushort4 o;
      o.x = f2bf(v.x); o.y = f2bf(v.y); o.z = f2bf(v.z); o.w = f2bf(v.w);
      reinterpret_cast<ushort4*>(xb + rowoff)[soff >> 2] = o;
      xT[soff + 0][c] = o.x;
      xT[soff + 1][c] = o.y;
      xT[soff + 2][c] = o.z;
      xT[soff + 3][c] = o.w;
    }
  }
  __syncthreads();

  const int w    = t >> 6;        // 0..7
  const int lane = t & 63;
  const int q    = lane >> 4;
  const int mr   = lane & 15;
  const int wrow = (w & 3) * 16;  // s-rows within tile
  const int half = w >> 2;        // 0: theta->Qt, 1: phi->Kt

  bfrag a[8];
  {
    const bfrag* rp = reinterpret_cast<const bfrag*>(&xT[wrow + mr][0]);
    #pragma unroll
    for (int k = 0; k < 8; ++k) a[k] = rp[k * 4 + q];
  }

  const unsigned short* wsel = half ? phw : thw;
  unsigned short*       osel = half ? Kt  : Qt;
  const float           sc   = half ? 1.0f : QSCALE;
  const bfrag* wp = reinterpret_cast<const bfrag*>(wsel);
  #pragma unroll
  for (int nt = 0; nt < 8; ++nt) {
    f32x4 acc = {0.f, 0.f, 0.f, 0.f};
    #pragma unroll
    for (int k = 0; k < 8; ++k) {
      bfrag b = wp[(nt * 16 + mr) * (CH / 8) + k * 4 + q];
      acc = __builtin_amdgcn_mfma_f32_16x16x32_bf16(a[k], b, acc, 0, 0, 0);
    }
    #pragma unroll
    for (int i = 0; i < 4; ++i) {
      const int srow = s0 + wrow + q * 4 + i;
      osel[((size_t)n * SS + srow) * EE + nt * 16 + mr] = f2bf(acc[i] * sc);
    }
  }
}

// ---------------------------------------------------------------------------
// Pass 2 (fused): flash attention + projection + residual.
// Round-3 kernel (117.5 us measured) + ONE change: the two in-loop
// __syncthreads (which compile to s_waitcnt vmcnt(0) lgkmcnt(0) + s_barrier,
// draining ALL outstanding K/V global loads twice per iteration) are replaced
// by lgkmcnt-only barriers. Both barriers only order LDS traffic (S_lds /
// P_lds / row_*); the global V/K prefetches land in registers and carry no
// cross-thread hazard, so they may stay in flight across the barrier. This
// attacks the measured per-CU ingest cap (27.6 GB/s = 3MB/108.6us, exact in
// r0/r1/r3): concurrency was drain-limited, not bandwidth-limited.
// ---------------------------------------------------------------------------
__global__ __launch_bounds__(512, 2) void pass2_attn(
    const unsigned short* __restrict__ Qt,
    const unsigned short* __restrict__ Kt,
    const unsigned short* __restrict__ xb,
    const unsigned short* __restrict__ pwb,
    const float* __restrict__ x,
    float* __restrict__ out)
{
  //   [0      .. 33792)  S_lds  float[64][132]   | epilogue: Y_lds u16[64][264]
  //   [33792  .. 51200)  P_lds  u16[64][136]
  //   [51200  .. 51456)  row_m  float[64]
  //   [51456  .. 51712)  row_l  float[64]
  //   [51712  .. 51968)  row_alpha float[64]
  __shared__ __align__(16) unsigned char SMEM[51968];
  float          (*S_lds)[132] = reinterpret_cast<float(*)[132]>(SMEM);
  unsigned short (*P_lds)[136] = reinterpret_cast<unsigned short(*)[136]>(SMEM + 33792);
  float* row_m     = reinterpret_cast<float*>(SMEM + 51200);
  float* row_l     = reinterpret_cast<float*>(SMEM + 51456);
  float* row_alpha = reinterpret_cast<float*>(SMEM + 51712);

  const int t    = threadIdx.x;
  const int id   = blockIdx.x;
  const int xcd  = id & 7;                    // presumed HW XCD of this block
  const int n    = xcd >> 1;                  // pin each image to 2 XCDs
  const int s0   = ((id >> 3) * 2 + (xcd & 1)) * 64;  // bijective: 64 tiles/n
  const int w    = t >> 6;      // 0..7
  const int lane = t & 63;
  const int q    = lane >> 4;
  const int mr   = lane & 15;

  if (t < 64) { row_m[t] = -INFINITY; row_l[t] = 0.f; }

  // Q fragments (64 rows x 128 e) in registers for the whole loop
  bfrag qa[4][4];
  #pragma unroll
  for (int ms = 0; ms < 4; ++ms) {
    const bfrag* rp = reinterpret_cast<const bfrag*>(
        Qt + ((size_t)n * SS + s0 + ms * 16 + mr) * EE);
    #pragma unroll
    for (int k = 0; k < 4; ++k) qa[ms][k] = rp[k * 4 + q];
  }

  f32x4 o_acc[4][2];
  #pragma unroll
  for (int ms = 0; ms < 4; ++ms)
    #pragma unroll
    for (int nt = 0; nt < 2; ++nt) o_acc[ms][nt] = (f32x4){0.f, 0.f, 0.f, 0.f};

  // K fragments for iter 0 (wave w -> key col block w)
  bfrag kb[4];
  {
    const bfrag* rp = reinterpret_cast<const bfrag*>(
        Kt + ((size_t)n * SS + w * 16 + mr) * EE);
    #pragma unroll
    for (int k = 0; k < 4; ++k) kb[k] = rp[k * 4 + q];
  }

  for (int t0 = 0; t0 < SS; t0 += 128) {
    // ---- prefetch V fragments for THIS iter (consumed after softmax) ----
    bfrag vb[4][2];
    #pragma unroll
    for (int nt = 0; nt < 2; ++nt) {
      const int c = w * 32 + nt * 16 + mr;
      const bfrag* vp = reinterpret_cast<const bfrag*>(
          xb + ((size_t)n * CH + c) * SS + t0);
      #pragma unroll
      for (int kk = 0; kk < 4; ++kk) vb[kk][nt] = vp[kk * 4 + q];
    }

    // ---- QK^T: wave w -> 16 key cols ----
    #pragma unroll
    for (int ms = 0; ms < 4; ++ms) {
      f32x4 acc = {0.f, 0.f, 0.f, 0.f};
      #pragma unroll
      for (int k = 0; k < 4; ++k)
        acc = __builtin_amdgcn_mfma_f32_16x16x32_bf16(qa[ms][k], kb[k], acc, 0, 0, 0);
      #pragma unroll
      for (int i = 0; i < 4; ++i)
        S_lds[ms * 16 + q * 4 + i][w * 16 + mr] = acc[i];
    }
    lds_barrier();   // LDS-only: V loads stay in flight

    // ---- prefetch K fragments for NEXT iter ----
    {
      const int t1 = t0 + 128;
      if (t1 < SS) {
        const bfrag* rp = reinterpret_cast<const bfrag*>(
            Kt + ((size_t)n * SS + t1 + w * 16 + mr) * EE);
        #pragma unroll
        for (int k = 0; k < 4; ++k) kb[k] = rp[k * 4 + q];
      }
    }

    // ---- online softmax: 8 lanes/row, float4 reads, ushort8 P writes ----
    {
      const int r  = t >> 3;
      const int cg = t & 7;
      const float4* srow = reinterpret_cast<const float4*>(&S_lds[r][cg * 16]);
      float4 v0 = srow[0], v1 = srow[1], v2 = srow[2], v3 = srow[3];
      float vmax = fmaxf(fmaxf(fmaxf(v0.x, v0.y), fmaxf(v0.z, v0.w)),
                         fmaxf(fmaxf(v1.x, v1.y), fmaxf(v1.z, v1.w)));
      vmax = fmaxf(vmax, fmaxf(fmaxf(fmaxf(v2.x, v2.y), fmaxf(v2.z, v2.w)),
                               fmaxf(fmaxf(v3.x, v3.y), fmaxf(v3.z, v3.w))));
      vmax = fmaxf(vmax, __shfl_xor(vmax, 1, 8));
      vmax = fmaxf(vmax, __shfl_xor(vmax, 2, 8));
      vmax = fmaxf(vmax, __shfl_xor(vmax, 4, 8));
      const float m_old = row_m[r];
      const float m_new = fmaxf(m_old, vmax);

      float p[16];
      p[0]=__expf(v0.x-m_new); p[1]=__expf(v0.y-m_new); p[2]=__expf(v0.z-m_new); p[3]=__expf(v0.w-m_new);
      p[4]=__expf(v1.x-m_new); p[5]=__expf(v1.y-m_new); p[6]=__expf(v1.z-m_new); p[7]=__expf(v1.w-m_new);
      p[8]=__expf(v2.x-m_new); p[9]=__expf(v2.y-m_new); p[10]=__expf(v2.z-m_new); p[11]=__expf(v2.w-m_new);
      p[12]=__expf(v3.x-m_new); p[13]=__expf(v3.y-m_new); p[14]=__expf(v3.z-m_new); p[15]=__expf(v3.w-m_new);
      float sum = 0.f;
      u16x8 pk0, pk1;
      #pragma unroll
      for (int j = 0; j < 8; ++j) { sum += p[j];     pk0[j] = f2bf(p[j]); }
      #pragma unroll
      for (int j = 0; j < 8; ++j) { sum += p[8 + j]; pk1[j] = f2bf(p[8 + j]); }
      *reinterpret_cast<u16x8*>(&P_lds[r][cg * 16])     = pk0;
      *reinterpret_cast<u16x8*>(&P_lds[r][cg * 16 + 8]) = pk1;
      sum += __shfl_xor(sum, 1, 8);
      sum += __shfl_xor(sum, 2, 8);
      sum += __shfl_xor(sum, 4, 8);
      if (cg == 0) {
        const float al = __expf(m_old - m_new);   // exp(-inf)=0 on iter 0
        row_alpha[r] = al;
        row_m[r]     = m_new;
        row_l[r]     = row_l[r] * al + sum;
      }
    }
    lds_barrier();   // LDS-only: K-next loads stay in flight

    // ---- rescale O, then O += P @ V ----
    #pragma unroll
    for (int ms = 0; ms < 4; ++ms) {
      float al[4];
      #pragma unroll
      for (int i = 0; i < 4; ++i) al[i] = row_alpha[ms * 16 + q * 4 + i];
      #pragma unroll
      for (int nt = 0; nt < 2; ++nt)
        #pragma unroll
        for (int i = 0; i < 4; ++i) o_acc[ms][nt][i] *= al[i];
    }

    #pragma unroll
    for (int kk = 0; kk < 4; ++kk) {
      bfrag pa[4];
      #pragma unroll
      for (int ms = 0; ms < 4; ++ms)
        pa[ms] = reinterpret_cast<const bfrag*>(&P_lds[ms * 16 + mr][0])[kk * 4 + q];
      #pragma unroll
      for (int nt = 0; nt < 2; ++nt)
        #pragma unroll
        for (int ms = 0; ms < 4; ++ms)
          o_acc[ms][nt] = __builtin_amdgcn_mfma_f32_16x16x32_bf16(
              pa[ms], vb[kk][nt], o_acc[ms][nt], 0, 0, 0);
    }
  }

  // ---- fused epilogue: Y -> LDS, then out = x + pw @ Y^T ----
  __syncthreads();   // full barrier: everyone done with S_lds/P_lds
  unsigned short (*Y_lds)[CH + 8] =
      reinterpret_cast<unsigned short(*)[CH + 8]>(SMEM);  // 64*264*2 = 33792 B

  #pragma unroll
  for (int ms = 0; ms < 4; ++ms) {
    float inv[4];
    #pragma unroll
    for (int i = 0; i < 4; ++i) inv[i] = 1.0f / row_l[ms * 16 + q * 4 + i];
    #pragma unroll
    for (int nt = 0; nt < 2; ++nt) {
      const int c = w * 32 + nt * 16 + mr;
      #pragma unroll
      for (int i = 0; i < 4; ++i)
        Y_lds[ms * 16 + q * 4 + i][c] = f2bf(o_acc[ms][nt][i] * inv[i]);
    }
  }
  __syncthreads();

  // projection: wave w computes output rows o = w*32 .. w*32+31
  #pragma unroll
  for (int ot = 0; ot < 2; ++ot) {
    const int o0 = w * 32 + ot * 16;
    bfrag a[8];
    {
      const bfrag* ap = reinterpret_cast<const bfrag*>(pwb + (o0 + mr) * CH);
      #pragma unroll
      for (int k = 0; k < 8; ++k) a[k] = ap[k * 4 + q];
    }
    #pragma unroll
    for (int st = 0; st < 4; ++st) {
      f32x4 acc = {0.f, 0.f, 0.f, 0.f};
      const bfrag* bp = reinterpret_cast<const bfrag*>(&Y_lds[st * 16 + mr][0]);
      #pragma unroll
      for (int k = 0; k < 8; ++k)
        acc = __builtin_amdgcn_mfma_f32_16x16x32_bf16(a[k], bp[k * 4 + q], acc, 0, 0, 0);
      #pragma unroll
      for (int i = 0; i < 4; ++i) {
        const int o = o0 + q * 4 + i;
        const int s = s0 + st * 16 + mr;
        const size_t idx = ((size_t)n * CH + o) * SS + s;
        out[idx] = x[idx] + acc[i];
      }
    }
  }
}

// ---------------------------------------------------------------------------
extern "C" void kernel_launch(void* const* d_in, const int* in_sizes, int n_in,
                              void* d_out, int out_size, void* d_ws, size_t ws_size,
                              hipStream_t stream) {
  const float* x   = (const float*)d_in[0];
  const float* thw = (const float*)d_in[1];
  const float* phw = (const float*)d_in[2];
  const float* pw  = (const float*)d_in[3];
  float* out = (float*)d_out;

  unsigned short* xb   = (unsigned short*)d_ws;               // 8 MB
  unsigned short* Qt   = xb + (size_t)NB * CH * SS;           // 4 MB
  unsigned short* Kt   = Qt + (size_t)NB * SS * EE;           // 4 MB
  unsigned short* thwb = Kt + (size_t)NB * SS * EE;           // 64 KB
  unsigned short* phwb = thwb + EE * CH;                      // 64 KB
  unsigned short* pwb  = phwb + EE * CH;                      // 128 KB

  const int nw4 = EE * CH / 4;
  const int np4 = CH * CH / 4;
  const int totw4 = 2 * nw4 + np4;
  cvt_w<<<(totw4 + 255) / 256, 256, 0, stream>>>(thw, phw, pw, thwb, phwb, pwb);

  pass1_qk  <<<dim3(SS / 64, NB), 512, 0, stream>>>(x, thwb, phwb, xb, Qt, Kt);
  pass2_attn<<<dim3(NB * SS / 64), 512, 0, stream>>>(Qt, Kt, xb, pwb, x, out);
}

// Round 7
// 190.489 us; speedup vs baseline: 1.5147x; 1.0281x over previous
//
#include <hip/hip_runtime.h>
#include <cstdint>
#include <cstddef>

#define NB 4
#define CH 256
#define SS 4096
#define EE 128
#define QSCALE 0.08838834764831845f /* 1/sqrt(128) */

typedef __attribute__((ext_vector_type(8))) short bfrag;          // 8 bf16 = 4 VGPR
typedef __attribute__((ext_vector_type(8))) unsigned short u16x8; // 16B ld/st
typedef __attribute__((ext_vector_type(8))) _Float16 h16x8;       // 16B fp16
typedef __attribute__((ext_vector_type(4))) float f32x4;          // MFMA acc

__device__ __forceinline__ unsigned short f2bf(float f) {
  union { float f; unsigned int u; } v; v.f = f;
  unsigned int u = v.u;
  unsigned int r = u + 0x7FFFu + ((u >> 16) & 1u);  // RNE
  return (unsigned short)(r >> 16);
}

// LDS-only barrier: waits DS ops, leaves global loads in flight.
__device__ __forceinline__ void lds_barrier() {
  asm volatile("s_waitcnt lgkmcnt(0)" ::: "memory");
  __builtin_amdgcn_s_barrier();
}

// ---------------------------------------------------------------------------
// Pass 0: weights-only fp32 -> bf16
// ---------------------------------------------------------------------------
__global__ __launch_bounds__(256) void cvt_w(
    const float* __restrict__ thw, const float* __restrict__ phw,
    const float* __restrict__ pw,
    unsigned short* __restrict__ thwb, unsigned short* __restrict__ phwb,
    unsigned short* __restrict__ pwb)
{
  const int nw4 = EE * CH / 4;   // 8192
  const int np4 = CH * CH / 4;   // 16384
  int i = blockIdx.x * 256 + threadIdx.x;
  const float* src; unsigned short* dst; int off;
  if      (i < nw4)           { src = thw; dst = thwb; off = i; }
  else if (i < 2 * nw4)       { src = phw; dst = phwb; off = i - nw4; }
  else if (i < 2 * nw4 + np4) { src = pw;  dst = pwb;  off = i - 2 * nw4; }
  else return;
  float4 v = reinterpret_cast<const float4*>(src)[off];
  ushort4 o;
  o.x = f2bf(v.x); o.y = f2bf(v.y); o.z = f2bf(v.z); o.w = f2bf(v.w);
  reinterpret_cast<ushort4*>(dst)[off] = o;
}

// ---------------------------------------------------------------------------
// Pass 1 (fused): x fp32->bf16 (xb byproduct) + theta/phi projections.
// ---------------------------------------------------------------------------
__global__ __launch_bounds__(512) void pass1_qk(
    const float* __restrict__ x,
    const unsigned short* __restrict__ thw,
    const unsigned short* __restrict__ phw,
    unsigned short* __restrict__ xb,
    unsigned short* __restrict__ Qt,
    unsigned short* __restrict__ Kt)
{
  __shared__ unsigned short xT[64][CH + 8];
  const int t  = threadIdx.x;
  const int n  = blockIdx.y;
  const int s0 = blockIdx.x * 64;

  {
    const int soff = (t & 15) * 4;
    const int c0   = t >> 4;           // 0..31
    #pragma unroll
    for (int ci = 0; ci < 8; ++ci) {
      const int c = c0 + ci * 32;
      const size_t rowoff = ((size_t)n * CH + c) * SS + s0;
      float4 v = reinterpret_cast<const float4*>(x + rowoff)[soff >> 2];
      ushort4 o;
      o.x = f2bf(v.x); o.y = f2bf(v.y); o.z = f2bf(v.z); o.w = f2bf(v.w);
      reinterpret_cast<ushort4*>(xb + rowoff)[soff >> 2] = o;
      xT[soff + 0][c] = o.x;
      xT[soff + 1][c] = o.y;
      xT[soff + 2][c] = o.z;
      xT[soff + 3][c] = o.w;
    }
  }
  __syncthreads();

  const int w    = t >> 6;        // 0..7
  const int lane = t & 63;
  const int q    = lane >> 4;
  const int mr   = lane & 15;
  const int wrow = (w & 3) * 16;
  const int half = w >> 2;        // 0: theta->Qt, 1: phi->Kt

  bfrag a[8];
  {
    const bfrag* rp = reinterpret_cast<const bfrag*>(&xT[wrow + mr][0]);
    #pragma unroll
    for (int k = 0; k < 8; ++k) a[k] = rp[k * 4 + q];
  }

  const unsigned short* wsel = half ? phw : thw;
  unsigned short*       osel = half ? Kt  : Qt;
  const float           sc   = half ? 1.0f : QSCALE;
  const bfrag* wp = reinterpret_cast<const bfrag*>(wsel);
  #pragma unroll
  for (int nt = 0; nt < 8; ++nt) {
    f32x4 acc = {0.f, 0.f, 0.f, 0.f};
    #pragma unroll
    for (int k = 0; k < 8; ++k) {
      bfrag b = wp[(nt * 16 + mr) * (CH / 8) + k * 4 + q];
      acc = __builtin_amdgcn_mfma_f32_16x16x32_bf16(a[k], b, acc, 0, 0, 0);
    }
    #pragma unroll
    for (int i = 0; i < 4; ++i) {
      const int srow = s0 + wrow + q * 4 + i;
      osel[((size_t)n * SS + srow) * EE + nt * 16 + mr] = f2bf(acc[i] * sc);
    }
  }
}

// ---------------------------------------------------------------------------
// Pass 2a (split path): partial flash attention. Q-tile 128, keys split 2-way
// across blocks -> per-block K/V stream 1.5 MB (aggregate 384 MB, half of the
// measured 768 MB at the fixed ~27.6 GB/s/CU ingest law). Writes normalized
// partial O (fp32 or fp16, host-gated) + per-row (m, l).
// ---------------------------------------------------------------------------
__global__ __launch_bounds__(512, 2) void pass2a(
    const unsigned short* __restrict__ Qt,
    const unsigned short* __restrict__ Kt,
    const unsigned short* __restrict__ xb,
    void* __restrict__ Opart_,
    float* __restrict__ ML,
    int use32)
{
  //   [0      .. 67584)   S_lds  f32[128][132]
  //   [67584  .. 102400)  P_lds  u16[128][136]
  //   [102400 .. 137216)  Q_lds  u16[128][136]
  //   [137216 .. 138752)  row_m / row_l / row_alpha  f32[128] each
  __shared__ __align__(16) unsigned char SMEM[138752];
  float          (*S_lds)[132] = reinterpret_cast<float(*)[132]>(SMEM);
  unsigned short (*P_lds)[136] = reinterpret_cast<unsigned short(*)[136]>(SMEM + 67584);
  unsigned short (*Q_lds)[136] = reinterpret_cast<unsigned short(*)[136]>(SMEM + 102400);
  float* row_m     = reinterpret_cast<float*>(SMEM + 137216);
  float* row_l     = reinterpret_cast<float*>(SMEM + 137728);
  float* row_alpha = reinterpret_cast<float*>(SMEM + 138240);

  float*    Of32 = reinterpret_cast<float*>(Opart_);
  _Float16* Oh16 = reinterpret_cast<_Float16*>(Opart_);

  const int t     = threadIdx.x;
  const int id    = blockIdx.x;
  const int xcd   = id & 7;
  const int n     = xcd >> 1;
  const int h     = xcd & 1;         // key half
  const int qt    = id >> 3;         // 0..31
  const int s0    = qt * 128;
  const int kbase = h * 2048;

  const int w    = t >> 6;      // 0..7
  const int lane = t & 63;
  const int q    = lane >> 4;
  const int mr   = lane & 15;

  if (t < 128) { row_m[t] = -INFINITY; row_l[t] = 0.f; }

  // stage the 128-row Q tile into LDS (coalesced 16B chunks)
  {
    const int col = (t & 15) * 8;
    #pragma unroll
    for (int j = 0; j < 4; ++j) {
      const int row = (t >> 4) + j * 32;
      *reinterpret_cast<u16x8*>(&Q_lds[row][col]) =
          *reinterpret_cast<const u16x8*>(
              Qt + ((size_t)n * SS + s0 + row) * EE + col);
    }
  }

  f32x4 o_accA[4][2], o_accB[4][2];
  #pragma unroll
  for (int ms = 0; ms < 4; ++ms)
    #pragma unroll
    for (int nt = 0; nt < 2; ++nt) {
      o_accA[ms][nt] = (f32x4){0.f, 0.f, 0.f, 0.f};
      o_accB[ms][nt] = (f32x4){0.f, 0.f, 0.f, 0.f};
    }

  __syncthreads();   // Q_lds + row init visible

  // K fragments for iter 0 (wave w -> key cols w*16..+15)
  bfrag kb[4];
  {
    const bfrag* rp = reinterpret_cast<const bfrag*>(
        Kt + ((size_t)n * SS + kbase + w * 16 + mr) * EE);
    #pragma unroll
    for (int k = 0; k < 4; ++k) kb[k] = rp[k * 4 + q];
  }

#define QK_HALF(RB)                                                          \
  do {                                                                       \
    _Pragma("unroll")                                                        \
    for (int ms = 0; ms < 4; ++ms) {                                         \
      f32x4 acc = {0.f, 0.f, 0.f, 0.f};                                      \
      _Pragma("unroll")                                                      \
      for (int k = 0; k < 4; ++k) {                                          \
        bfrag aq = *reinterpret_cast<const bfrag*>(                          \
            &Q_lds[(RB) + ms * 16 + mr][(k * 4 + q) * 8]);                   \
        acc = __builtin_amdgcn_mfma_f32_16x16x32_bf16(aq, kb[k], acc, 0,0,0);\
      }                                                                      \
      _Pragma("unroll")                                                      \
      for (int i = 0; i < 4; ++i)                                            \
        S_lds[(RB) + ms * 16 + q * 4 + i][w * 16 + mr] = acc[i];             \
    }                                                                        \
  } while (0)

#define PV_HALF(OACC, RB)                                                    \
  do {                                                                       \
    _Pragma("unroll")                                                        \
    for (int ms = 0; ms < 4; ++ms) {                                         \
      float al[4];                                                           \
      _Pragma("unroll")                                                      \
      for (int i = 0; i < 4; ++i) al[i] = row_alpha[(RB) + ms*16 + q*4 + i]; \
      _Pragma("unroll")                                                      \
      for (int nt = 0; nt < 2; ++nt)                                         \
        _Pragma("unroll")                                                    \
        for (int i = 0; i < 4; ++i) OACC[ms][nt][i] *= al[i];                \
    }                                                                        \
    _Pragma("unroll")                                                        \
    for (int kk = 0; kk < 4; ++kk) {                                         \
      bfrag pa[4];                                                           \
      _Pragma("unroll")                                                      \
      for (int ms = 0; ms < 4; ++ms)                                         \
        pa[ms] = reinterpret_cast<const bfrag*>(                             \
            &P_lds[(RB) + ms * 16 + mr][0])[kk * 4 + q];                     \
      _Pragma("unroll")                                                      \
      for (int nt = 0; nt < 2; ++nt)                                         \
        _Pragma("unroll")                                                    \
        for (int ms = 0; ms < 4; ++ms)                                       \
          OACC[ms][nt] = __builtin_amdgcn_mfma_f32_16x16x32_bf16(            \
              pa[ms], vb[kk][nt], OACC[ms][nt], 0, 0, 0);                    \
    }                                                                        \
  } while (0)

  for (int t0 = 0; t0 < 2048; t0 += 128) {
    // ---- V fragments for THIS iter (shared by both halves) ----
    bfrag vb[4][2];
    #pragma unroll
    for (int nt = 0; nt < 2; ++nt) {
      const int c = w * 32 + nt * 16 + mr;
      const bfrag* vp = reinterpret_cast<const bfrag*>(
          xb + ((size_t)n * CH + c) * SS + kbase + t0);
      #pragma unroll
      for (int kk = 0; kk < 4; ++kk) vb[kk][nt] = vp[kk * 4 + q];
    }

    // ---- QK^T for both 64-row halves (kb reused) ----
    QK_HALF(0);
    QK_HALF(64);
    lds_barrier();

    // ---- prefetch K fragments for NEXT iter ----
    if (t0 + 128 < 2048) {
      const bfrag* rp = reinterpret_cast<const bfrag*>(
          Kt + ((size_t)n * SS + kbase + t0 + 128 + w * 16 + mr) * EE);
      #pragma unroll
      for (int k = 0; k < 4; ++k) kb[k] = rp[k * 4 + q];
    }

    // ---- online softmax: 8 lanes/row, rows 0..63 then 64..127 ----
    #pragma unroll
    for (int sh = 0; sh < 2; ++sh) {
      const int r  = sh * 64 + (t >> 3);
      const int cg = t & 7;
      const float4* srow = reinterpret_cast<const float4*>(&S_lds[r][cg * 16]);
      float4 v0 = srow[0], v1 = srow[1], v2 = srow[2], v3 = srow[3];
      float vmax = fmaxf(fmaxf(fmaxf(v0.x, v0.y), fmaxf(v0.z, v0.w)),
                         fmaxf(fmaxf(v1.x, v1.y), fmaxf(v1.z, v1.w)));
      vmax = fmaxf(vmax, fmaxf(fmaxf(fmaxf(v2.x, v2.y), fmaxf(v2.z, v2.w)),
                               fmaxf(fmaxf(v3.x, v3.y), fmaxf(v3.z, v3.w))));
      vmax = fmaxf(vmax, __shfl_xor(vmax, 1, 8));
      vmax = fmaxf(vmax, __shfl_xor(vmax, 2, 8));
      vmax = fmaxf(vmax, __shfl_xor(vmax, 4, 8));
      const float m_old = row_m[r];
      const float m_new = fmaxf(m_old, vmax);

      float p[16];
      p[0]=__expf(v0.x-m_new); p[1]=__expf(v0.y-m_new); p[2]=__expf(v0.z-m_new); p[3]=__expf(v0.w-m_new);
      p[4]=__expf(v1.x-m_new); p[5]=__expf(v1.y-m_new); p[6]=__expf(v1.z-m_new); p[7]=__expf(v1.w-m_new);
      p[8]=__expf(v2.x-m_new); p[9]=__expf(v2.y-m_new); p[10]=__expf(v2.z-m_new); p[11]=__expf(v2.w-m_new);
      p[12]=__expf(v3.x-m_new); p[13]=__expf(v3.y-m_new); p[14]=__expf(v3.z-m_new); p[15]=__expf(v3.w-m_new);
      float sum = 0.f;
      u16x8 pk0, pk1;
      #pragma unroll
      for (int j = 0; j < 8; ++j) { sum += p[j];     pk0[j] = f2bf(p[j]); }
      #pragma unroll
      for (int j = 0; j < 8; ++j) { sum += p[8 + j]; pk1[j] = f2bf(p[8 + j]); }
      *reinterpret_cast<u16x8*>(&P_lds[r][cg * 16])     = pk0;
      *reinterpret_cast<u16x8*>(&P_lds[r][cg * 16 + 8]) = pk1;
      sum += __shfl_xor(sum, 1, 8);
      sum += __shfl_xor(sum, 2, 8);
      sum += __shfl_xor(sum, 4, 8);
      if (cg == 0) {
        const float al = __expf(m_old - m_new);   // exp(-inf)=0 on iter 0
        row_alpha[r] = al;
        row_m[r]     = m_new;
        row_l[r]     = row_l[r] * al + sum;
      }
    }
    lds_barrier();

    // ---- rescale + PV for both halves (vb reused) ----
    PV_HALF(o_accA, 0);
    PV_HALF(o_accB, 64);
  }

  // ---- epilogue: normalized partials + (m,l) ----
  const size_t p = ((size_t)(n * 32 + qt)) * 2 + h;

#define EPI_HALF(OACC, RB)                                                   \
  do {                                                                       \
    _Pragma("unroll")                                                        \
    for (int ms = 0; ms < 4; ++ms) {                                         \
      float inv[4];                                                          \
      _Pragma("unroll")                                                      \
      for (int i = 0; i < 4; ++i)                                            \
        inv[i] = 1.0f / row_l[(RB) + ms * 16 + q * 4 + i];                   \
      _Pragma("unroll")                                                      \
      for (int nt = 0; nt < 2; ++nt)                                         \
        _Pragma("unroll")                                                    \
        for (int i = 0; i < 4; ++i) {                                        \
          const size_t oi =                                                  \
              (p * 128 + (RB) + ms * 16 + q * 4 + i) * 256 +                 \
              w * 32 + nt * 16 + mr;                                         \
          const float yv = OACC[ms][nt][i] * inv[i];                         \
          if (use32) Of32[oi] = yv; else Oh16[oi] = (_Float16)yv;            \
        }                                                                    \
    }                                                                        \
  } while (0)

  EPI_HALF(o_accA, 0);
  EPI_HALF(o_accB, 64);
  if (t < 128) {
    ML[p * 256 + t * 2]     = row_m[t];
    ML[p * 256 + t * 2 + 1] = row_l[t];
  }
}

// ---------------------------------------------------------------------------
// Pass 2b (split path): merge the two key-halves + projection + residual.
// ---------------------------------------------------------------------------
__global__ __launch_bounds__(512) void pass2b(
    const void* __restrict__ Opart_,
    const float* __restrict__ ML,
    const unsigned short* __restrict__ pwb,
    const float* __restrict__ x,
    float* __restrict__ out,
    int use32)
{
  __shared__ __align__(16) unsigned char SMEM[34816];
  unsigned short (*Y_lds)[CH + 8] =
      reinterpret_cast<unsigned short(*)[CH + 8]>(SMEM);   // 64*264*2 = 33792
  float* w0 = reinterpret_cast<float*>(SMEM + 33792);      // 64 f32
  float* w1 = reinterpret_cast<float*>(SMEM + 34048);      // 64 f32

  const float*    Of32 = reinterpret_cast<const float*>(Opart_);
  const _Float16* Oh16 = reinterpret_cast<const _Float16*>(Opart_);

  const int t   = threadIdx.x;
  const int id  = blockIdx.x;
  const int n   = id >> 6;
  const int sub = id & 63;
  const int s0  = sub * 64;
  const int qt  = sub >> 1;
  const int rb  = (sub & 1) * 64;          // row range within the q-tile
  const size_t p0 = ((size_t)(n * 32 + qt)) * 2;

  if (t < 64) {
    const float ma = ML[p0 * 256 + (rb + t) * 2];
    const float la = ML[p0 * 256 + (rb + t) * 2 + 1];
    const float mb = ML[(p0 + 1) * 256 + (rb + t) * 2];
    const float lb = ML[(p0 + 1) * 256 + (rb + t) * 2 + 1];
    const float m  = fmaxf(ma, mb);
    const float e0 = __expf(ma - m) * la;
    const float e1 = __expf(mb - m) * lb;
    const float iL = 1.0f / (e0 + e1);
    w0[t] = e0 * iL;
    w1[t] = e1 * iL;
  }
  __syncthreads();

  // merge partials -> Y_lds (bf16)
  {
    const int r = t >> 3;
    #pragma unroll
    for (int seg = 0; seg < 4; ++seg) {
      const int c0 = (t & 7) * 8 + seg * 64;
      const size_t ai = (p0 * 128 + rb + r) * 256 + c0;
      const size_t bi = ((p0 + 1) * 128 + rb + r) * 256 + c0;
      float fa[8], fb[8];
      if (use32) {
        #pragma unroll
        for (int j = 0; j < 8; ++j) { fa[j] = Of32[ai + j]; fb[j] = Of32[bi + j]; }
      } else {
        h16x8 ha = *reinterpret_cast<const h16x8*>(Oh16 + ai);
        h16x8 hb = *reinterpret_cast<const h16x8*>(Oh16 + bi);
        #pragma unroll
        for (int j = 0; j < 8; ++j) { fa[j] = (float)ha[j]; fb[j] = (float)hb[j]; }
      }
      u16x8 y;
      #pragma unroll
      for (int j = 0; j < 8; ++j) y[j] = f2bf(fa[j] * w0[r] + fb[j] * w1[r]);
      *reinterpret_cast<u16x8*>(&Y_lds[r][c0]) = y;
    }
  }
  __syncthreads();

  // projection + residual: wave w -> output rows o = w*32 .. w*32+31
  const int w    = t >> 6;
  const int lane = t & 63;
  const int q    = lane >> 4;
  const int mr   = lane & 15;
  #pragma unroll
  for (int ot = 0; ot < 2; ++ot) {
    const int o0 = w * 32 + ot * 16;
    bfrag a[8];
    {
      const bfrag* ap = reinterpret_cast<const bfrag*>(pwb + (o0 + mr) * CH);
      #pragma unroll
      for (int k = 0; k < 8; ++k) a[k] = ap[k * 4 + q];
    }
    #pragma unroll
    for (int st = 0; st < 4; ++st) {
      f32x4 acc = {0.f, 0.f, 0.f, 0.f};
      const bfrag* bp = reinterpret_cast<const bfrag*>(&Y_lds[st * 16 + mr][0]);
      #pragma unroll
      for (int k = 0; k < 8; ++k)
        acc = __builtin_amdgcn_mfma_f32_16x16x32_bf16(a[k], bp[k * 4 + q], acc, 0, 0, 0);
      #pragma unroll
      for (int i = 0; i < 4; ++i) {
        const int o = o0 + q * 4 + i;
        const int s = s0 + st * 16 + mr;
        const size_t idx = ((size_t)n * CH + o) * SS + s;
        out[idx] = x[idx] + acc[i];
      }
    }
  }
}

// ---------------------------------------------------------------------------
// Fallback (ws too small for partials): round-5 fused full-key kernel,
// verbatim (measured 113.6 us; total 195.8 us). Fits in 16.6 MB workspace.
// ---------------------------------------------------------------------------
__global__ __launch_bounds__(512, 2) void pass2_full(
    const unsigned short* __restrict__ Qt,
    const unsigned short* __restrict__ Kt,
    const unsigned short* __restrict__ xb,
    const unsigned short* __restrict__ pwb,
    const float* __restrict__ x,
    float* __restrict__ out)
{
  __shared__ __align__(16) unsigned char SMEM[51968];
  float          (*S_lds)[132] = reinterpret_cast<float(*)[132]>(SMEM);
  unsigned short (*P_lds)[136] = reinterpret_cast<unsigned short(*)[136]>(SMEM + 33792);
  float* row_m     = reinterpret_cast<float*>(SMEM + 51200);
  float* row_l     = reinterpret_cast<float*>(SMEM + 51456);
  float* row_alpha = reinterpret_cast<float*>(SMEM + 51712);

  const int t    = threadIdx.x;
  const int id   = blockIdx.x;
  const int xcd  = id & 7;
  const int n    = xcd >> 1;
  const int s0   = ((id >> 3) * 2 + (xcd & 1)) * 64;
  const int w    = t >> 6;
  const int lane = t & 63;
  const int q    = lane >> 4;
  const int mr   = lane & 15;

  if (t < 64) { row_m[t] = -INFINITY; row_l[t] = 0.f; }

  bfrag qa[4][4];
  #pragma unroll
  for (int ms = 0; ms < 4; ++ms) {
    const bfrag* rp = reinterpret_cast<const bfrag*>(
        Qt + ((size_t)n * SS + s0 + ms * 16 + mr) * EE);
    #pragma unroll
    for (int k = 0; k < 4; ++k) qa[ms][k] = rp[k * 4 + q];
  }

  f32x4 o_acc[4][2];
  #pragma unroll
  for (int ms = 0; ms < 4; ++ms)
    #pragma unroll
    for (int nt = 0; nt < 2; ++nt) o_acc[ms][nt] = (f32x4){0.f, 0.f, 0.f, 0.f};

  bfrag kb[4];
  {
    const bfrag* rp = reinterpret_cast<const bfrag*>(
        Kt + ((size_t)n * SS + w * 16 + mr) * EE);
    #pragma unroll
    for (int k = 0; k < 4; ++k) kb[k] = rp[k * 4 + q];
  }

  for (int t0 = 0; t0 < SS; t0 += 128) {
    bfrag vb[4][2];
    #pragma unroll
    for (int nt = 0; nt < 2; ++nt) {
      const int c = w * 32 + nt * 16 + mr;
      const bfrag* vp = reinterpret_cast<const bfrag*>(
          xb + ((size_t)n * CH + c) * SS + t0);
      #pragma unroll
      for (int kk = 0; kk < 4; ++kk) vb[kk][nt] = vp[kk * 4 + q];
    }

    #pragma unroll
    for (int ms = 0; ms < 4; ++ms) {
      f32x4 acc = {0.f, 0.f, 0.f, 0.f};
      #pragma unroll
      for (int k = 0; k < 4; ++k)
        acc = __builtin_amdgcn_mfma_f32_16x16x32_bf16(qa[ms][k], kb[k], acc, 0, 0, 0);
      #pragma unroll
      for (int i = 0; i < 4; ++i)
        S_lds[ms * 16 + q * 4 + i][w * 16 + mr] = acc[i];
    }
    lds_barrier();

    {
      const int t1 = t0 + 128;
      if (t1 < SS) {
        const bfrag* rp = reinterpret_cast<const bfrag*>(
            Kt + ((size_t)n * SS + t1 + w * 16 + mr) * EE);
        #pragma unroll
        for (int k = 0; k < 4; ++k) kb[k] = rp[k * 4 + q];
      }
    }

    {
      const int r  = t >> 3;
      const int cg = t & 7;
      const float4* srow = reinterpret_cast<const float4*>(&S_lds[r][cg * 16]);
      float4 v0 = srow[0], v1 = srow[1], v2 = srow[2], v3 = srow[3];
      float vmax = fmaxf(fmaxf(fmaxf(v0.x, v0.y), fmaxf(v0.z, v0.w)),
                         fmaxf(fmaxf(v1.x, v1.y), fmaxf(v1.z, v1.w)));
      vmax = fmaxf(vmax, fmaxf(fmaxf(fmaxf(v2.x, v2.y), fmaxf(v2.z, v2.w)),
                               fmaxf(fmaxf(v3.x, v3.y), fmaxf(v3.z, v3.w))));
      vmax = fmaxf(vmax, __shfl_xor(vmax, 1, 8));
      vmax = fmaxf(vmax, __shfl_xor(vmax, 2, 8));
      vmax = fmaxf(vmax, __shfl_xor(vmax, 4, 8));
      const float m_old = row_m[r];
      const float m_new = fmaxf(m_old, vmax);

      float p[16];
      p[0]=__expf(v0.x-m_new); p[1]=__expf(v0.y-m_new); p[2]=__expf(v0.z-m_new); p[3]=__expf(v0.w-m_new);
      p[4]=__expf(v1.x-m_new); p[5]=__expf(v1.y-m_new); p[6]=__expf(v1.z-m_new); p[7]=__expf(v1.w-m_new);
      p[8]=__expf(v2.x-m_new); p[9]=__expf(v2.y-m_new); p[10]=__expf(v2.z-m_new); p[11]=__expf(v2.w-m_new);
      p[12]=__expf(v3.x-m_new); p[13]=__expf(v3.y-m_new); p[14]=__expf(v3.z-m_new); p[15]=__expf(v3.w-m_new);
      float sum = 0.f;
      u16x8 pk0, pk1;
      #pragma unroll
      for (int j = 0; j < 8; ++j) { sum += p[j];     pk0[j] = f2bf(p[j]); }
      #pragma unroll
      for (int j = 0; j < 8; ++j) { sum += p[8 + j]; pk1[j] = f2bf(p[8 + j]); }
      *reinterpret_cast<u16x8*>(&P_lds[r][cg * 16])     = pk0;
      *reinterpret_cast<u16x8*>(&P_lds[r][cg * 16 + 8]) = pk1;
      sum += __shfl_xor(sum, 1, 8);
      sum += __shfl_xor(sum, 2, 8);
      sum += __shfl_xor(sum, 4, 8);
      if (cg == 0) {
        const float al = __expf(m_old - m_new);
        row_alpha[r] = al;
        row_m[r]     = m_new;
        row_l[r]     = row_l[r] * al + sum;
      }
    }
    lds_barrier();

    #pragma unroll
    for (int ms = 0; ms < 4; ++ms) {
      float al[4];
      #pragma unroll
      for (int i = 0; i < 4; ++i) al[i] = row_alpha[ms * 16 + q * 4 + i];
      #pragma unroll
      for (int nt = 0; nt < 2; ++nt)
        #pragma unroll
        for (int i = 0; i < 4; ++i) o_acc[ms][nt][i] *= al[i];
    }

    #pragma unroll
    for (int kk = 0; kk < 4; ++kk) {
      bfrag pa[4];
      #pragma unroll
      for (int ms = 0; ms < 4; ++ms)
        pa[ms] = reinterpret_cast<const bfrag*>(&P_lds[ms * 16 + mr][0])[kk * 4 + q];
      #pragma unroll
      for (int nt = 0; nt < 2; ++nt)
        #pragma unroll
        for (int ms = 0; ms < 4; ++ms)
          o_acc[ms][nt] = __builtin_amdgcn_mfma_f32_16x16x32_bf16(
              pa[ms], vb[kk][nt], o_acc[ms][nt], 0, 0, 0);
    }
  }

  __syncthreads();
  unsigned short (*Y_lds)[CH + 8] =
      reinterpret_cast<unsigned short(*)[CH + 8]>(SMEM);

  #pragma unroll
  for (int ms = 0; ms < 4; ++ms) {
    float inv[4];
    #pragma unroll
    for (int i = 0; i < 4; ++i) inv[i] = 1.0f / row_l[ms * 16 + q * 4 + i];
    #pragma unroll
    for (int nt = 0; nt < 2; ++nt) {
      const int c = w * 32 + nt * 16 + mr;
      #pragma unroll
      for (int i = 0; i < 4; ++i)
        Y_lds[ms * 16 + q * 4 + i][c] = f2bf(o_acc[ms][nt][i] * inv[i]);
    }
  }
  __syncthreads();

  #pragma unroll
  for (int ot = 0; ot < 2; ++ot) {
    const int o0 = w * 32 + ot * 16;
    bfrag a[8];
    {
      const bfrag* ap = reinterpret_cast<const bfrag*>(pwb + (o0 + mr) * CH);
      #pragma unroll
      for (int k = 0; k < 8; ++k) a[k] = ap[k * 4 + q];
    }
    #pragma unroll
    for (int st = 0; st < 4; ++st) {
      f32x4 acc = {0.f, 0.f, 0.f, 0.f};
      const bfrag* bp = reinterpret_cast<const bfrag*>(&Y_lds[st * 16 + mr][0]);
      #pragma unroll
      for (int k = 0; k < 8; ++k)
        acc = __builtin_amdgcn_mfma_f32_16x16x32_bf16(a[k], bp[k * 4 + q], acc, 0, 0, 0);
      #pragma unroll
      for (int i = 0; i < 4; ++i) {
        const int o = o0 + q * 4 + i;
        const int s = s0 + st * 16 + mr;
        const size_t idx = ((size_t)n * CH + o) * SS + s;
        out[idx] = x[idx] + acc[i];
      }
    }
  }
}

// ---------------------------------------------------------------------------
extern "C" void kernel_launch(void* const* d_in, const int* in_sizes, int n_in,
                              void* d_out, int out_size, void* d_ws, size_t ws_size,
                              hipStream_t stream) {
  const float* x   = (const float*)d_in[0];
  const float* thw = (const float*)d_in[1];
  const float* phw = (const float*)d_in[2];
  const float* pw  = (const float*)d_in[3];
  float* out = (float*)d_out;

  unsigned short* xb   = (unsigned short*)d_ws;               // 8 MB
  unsigned short* Qt   = xb + (size_t)NB * CH * SS;           // 4 MB
  unsigned short* Kt   = Qt + (size_t)NB * SS * EE;           // 4 MB
  unsigned short* thwb = Kt + (size_t)NB * SS * EE;           // 64 KB
  unsigned short* phwb = thwb + EE * CH;                      // 64 KB
  unsigned short* pwb  = phwb + EE * CH;                      // 128 KB
  float*          ML   = (float*)(pwb + CH * CH);             // 256 KB
  void*           Opart = (void*)(ML + (size_t)256 * 128 * 2);

  // strict workspace gating (r6 crash root-cause: ungated fp16 partials)
  const size_t opart_off = (size_t)((char*)Opart - (char*)d_ws); // 17,301,504
  const size_t opart_elems = (size_t)256 * 128 * 256;            // 8,388,608
  const int fits32 = ws_size >= opart_off + opart_elems * 4;
  const int fits16 = ws_size >= opart_off + opart_elems * 2;

  const int nw4 = EE * CH / 4;
  const int np4 = CH * CH / 4;
  const int totw4 = 2 * nw4 + np4;
  cvt_w<<<(totw4 + 255) / 256, 256, 0, stream>>>(thw, phw, pw, thwb, phwb, pwb);

  pass1_qk<<<dim3(SS / 64, NB), 512, 0, stream>>>(x, thwb, phwb, xb, Qt, Kt);

  if (fits32 || fits16) {
    const int use32 = fits32 ? 1 : 0;
    pass2a<<<dim3(256), 512, 0, stream>>>(Qt, Kt, xb, Opart, ML, use32);
    pass2b<<<dim3(256), 512, 0, stream>>>(Opart, ML, pwb, x, out, use32);
  } else {
    pass2_full<<<dim3(NB * SS / 64), 512, 0, stream>>>(Qt, Kt, xb, pwb, x, out);
  }
}